// Round 1
// 356.240 us; speedup vs baseline: 1.1290x; 1.1290x over previous
//
#include <hip/hip_runtime.h>

#define NNODES 100000
#define NEDGES 1250000
#define IN_CH 128
#define HID 64
#define BN_EPS 1e-5f

#define NPAD 100352               // NNODES rounded to 256 multiple
#define NSCAN_BLOCKS 391          // ceil(100000/256)
#define DRANGE 12500              // NNODES / 8 (dst range per XCD)
#define FILL_CHUNK 2048           // edges per block in filtered count/fill
#define FILL_CHUNKS 611           // ceil(NEDGES / FILL_CHUNK)
#define GBLOCKS 6250              // gather blocks: 16 nodes each (4 waves x 4)

typedef __attribute__((ext_vector_type(8))) short s16x8;   // 8 bf16 (4 VGPRs)
typedef __attribute__((ext_vector_type(4))) float f32x4;

// bf16 <-> f32 helpers (bit-level, no __hip_bfloat16 class dependence)
__device__ __forceinline__ ushort f2bf(float f) {
    union { float f; unsigned int i; } c;
    c.f = f;
    unsigned int lsb = (c.i >> 16) & 1u;
    return (ushort)((c.i + 0x7FFFu + lsb) >> 16);   // round-to-nearest-even
}
__device__ __forceinline__ float bf2f(ushort u) {
    union { unsigned int i; float f; } c;
    c.i = (unsigned int)u << 16;
    return c.f;
}
__device__ __forceinline__ float asf(unsigned int i) {
    union { unsigned int i; float f; } c;
    c.i = i;
    return c.f;
}

// ---------------- CSR build (dst-range partitioned by XCD) ----------------
__global__ void csr_zero(int* cnt) {
    int i = blockIdx.x * blockDim.x + threadIdx.x;
    if (i < NNODES) cnt[i] = 0;
}

// block b -> XCD b&7 (round-robin dispatch heuristic) -> dst range
// [p*DRANGE, (p+1)*DRANGE). Each XCD streams the whole dst[] (redundant reads
// served by L2/L3) but its atomic lines stay XCD-local.
__global__ void csr_count(const int* __restrict__ dst, int* cnt) {
    int p = blockIdx.x & 7;
    int base = (blockIdx.x >> 3) * FILL_CHUNK;
    int lo = p * DRANGE, hi = lo + DRANGE;
#pragma unroll
    for (int k = 0; k < FILL_CHUNK / 256; ++k) {
        int e = base + k * 256 + threadIdx.x;
        if (e < NEDGES) {
            int d = dst[e];
            if (d >= lo && d < hi) atomicAdd(&cnt[d], 1);
        }
    }
}

// per-256-block exclusive scan of cnt -> row_ptr, block sums -> bsum.
// Also emits dis[i] = rsqrt(cnt[i]+1)  (degree incl. self-loop).
__global__ void scan1(const int* __restrict__ cnt, int* __restrict__ row_ptr,
                      int* __restrict__ bsum, float* __restrict__ dis) {
    __shared__ int s[256];
    int tid = threadIdx.x;
    int i = blockIdx.x * 256 + tid;
    int v = (i < NNODES) ? cnt[i] : 0;
    if (i < NNODES) dis[i] = rsqrtf((float)(v + 1));
    s[tid] = v;
    __syncthreads();
    for (int off = 1; off < 256; off <<= 1) {
        int t = (tid >= off) ? s[tid - off] : 0;
        __syncthreads();
        s[tid] += t;
        __syncthreads();
    }
    if (i < NNODES) row_ptr[i] = s[tid] - v;          // exclusive
    if (tid == 255) bsum[blockIdx.x] = s[255];        // block total
}

// single-block exclusive scan of the 391 block sums (512 threads, padded)
__global__ void scan2(int* bsum) {
    __shared__ int s[512];
    int tid = threadIdx.x;
    int v = (tid < NSCAN_BLOCKS) ? bsum[tid] : 0;
    s[tid] = v;
    __syncthreads();
    for (int off = 1; off < 512; off <<= 1) {
        int t = (tid >= off) ? s[tid - off] : 0;
        __syncthreads();
        s[tid] += t;
        __syncthreads();
    }
    if (tid < NSCAN_BLOCKS) bsum[tid] = s[tid] - v;   // exclusive
}

__global__ void scan3(int* __restrict__ row_ptr, const int* __restrict__ bsum,
                      int* __restrict__ pos) {
    int i = blockIdx.x * blockDim.x + threadIdx.x;
    if (i < NNODES) {
        int v = row_ptr[i] + bsum[i >> 8];
        row_ptr[i] = v;
        pos[i] = v;
    }
}

// Same dst-range filtering: XCD p only writes srcs slots belonging to its dst
// range -> contiguous ~640 KB region, fully merged in its local L2.
// Stores PRE-SHIFTED BYTE OFFSETS (src*128) so gather needs one v_add per edge.
__global__ void csr_fill(const int* __restrict__ src, const int* __restrict__ dst,
                         int* pos, int* __restrict__ srcs) {
    int p = blockIdx.x & 7;
    int base = (blockIdx.x >> 3) * FILL_CHUNK;
    int lo = p * DRANGE, hi = lo + DRANGE;
#pragma unroll
    for (int k = 0; k < FILL_CHUNK / 256; ++k) {
        int e = base + k * 256 + threadIdx.x;
        if (e < NEDGES) {
            int d = dst[e];
            if (d >= lo && d < hi) {
                int slot = atomicAdd(&pos[d], 1);
                srcs[slot] = src[e] << 7;             // byte offset into [node][64] bf16
            }
        }
    }
}

// ---------------- fc + bn0 + relu (MFMA, 16 nodes x 64 cols per wave) -----
// h0 stored NODE-MAJOR: h0[node][64] bf16 = 128 B rows (one gather unit).
__global__ __launch_bounds__(256) void fc_bn_relu(
        const float* __restrict__ x, const float* __restrict__ w,
        const float* __restrict__ b,
        const float* __restrict__ g, const float* __restrict__ be,
        const float* __restrict__ mu, const float* __restrict__ var,
        ushort* __restrict__ h0) {
    const int wave = threadIdx.x >> 6;
    const int lane = threadIdx.x & 63;
    const int m = lane & 15;
    const int q = lane >> 4;
    const int node_base = (blockIdx.x * 4 + wave) * 16;

    // B fragments: 4 k-chunks x 4 col-tiles (w is 128x64, L1/L2 resident)
    s16x8 bfrag[4][4];
#pragma unroll
    for (int kc = 0; kc < 4; ++kc)
#pragma unroll
        for (int ct = 0; ct < 4; ++ct)
#pragma unroll
            for (int j = 0; j < 8; ++j)
                bfrag[kc][ct][j] = (short)f2bf(w[(kc * 32 + q * 8 + j) * HID + ct * 16 + m]);

    f32x4 acc[4] = {{0,0,0,0},{0,0,0,0},{0,0,0,0},{0,0,0,0}};

    int row = node_base + m;
    if (row >= NNODES) row = NNODES - 1;             // clamp (stores guarded)
    const float4* xp = (const float4*)(x + (size_t)row * IN_CH + q * 8);

#pragma unroll
    for (int kc = 0; kc < 4; ++kc) {
        float4 a0 = xp[kc * 8 + 0];                  // k = kc*32 + q*8 + 0..3
        float4 a1 = xp[kc * 8 + 1];                  // k = kc*32 + q*8 + 4..7
        s16x8 af;
        af[0] = (short)f2bf(a0.x); af[1] = (short)f2bf(a0.y);
        af[2] = (short)f2bf(a0.z); af[3] = (short)f2bf(a0.w);
        af[4] = (short)f2bf(a1.x); af[5] = (short)f2bf(a1.y);
        af[6] = (short)f2bf(a1.z); af[7] = (short)f2bf(a1.w);
#pragma unroll
        for (int ct = 0; ct < 4; ++ct)
            acc[ct] = __builtin_amdgcn_mfma_f32_16x16x32_bf16(af, bfrag[kc][ct], acc[ct], 0, 0, 0);
    }

#pragma unroll
    for (int ct = 0; ct < 4; ++ct) {
        int col = ct * 16 + m;
        float sc = g[col] * rsqrtf(var[col] + BN_EPS);
        float off = (b[col] - mu[col]) * sc + be[col];
#pragma unroll
        for (int r = 0; r < 4; ++r) {
            int node = node_base + q * 4 + r;
            if (node < NNODES)
                h0[(size_t)node * HID + col] =
                    f2bf(fmaxf(acc[ct][r] * sc + off, 0.f));
        }
    }
}

// ---------------- conv matmul + source-side dis scale (MFMA) --------------
// h (bf16, node-major) -> hws (bf16, node-major), K = 64
__global__ __launch_bounds__(256) void conv_mm(
        const ushort* __restrict__ h, const float* __restrict__ w,
        const float* __restrict__ dis, ushort* __restrict__ hws) {
    const int wave = threadIdx.x >> 6;
    const int lane = threadIdx.x & 63;
    const int m = lane & 15;
    const int q = lane >> 4;
    const int node_base = (blockIdx.x * 4 + wave) * 16;

    s16x8 bfrag[2][4];
#pragma unroll
    for (int kc = 0; kc < 2; ++kc)
#pragma unroll
        for (int ct = 0; ct < 4; ++ct)
#pragma unroll
            for (int j = 0; j < 8; ++j)
                bfrag[kc][ct][j] = (short)f2bf(w[(kc * 32 + q * 8 + j) * HID + ct * 16 + m]);

    f32x4 acc[4] = {{0,0,0,0},{0,0,0,0},{0,0,0,0},{0,0,0,0}};

    int row = node_base + m;
    if (row >= NNODES) row = NNODES - 1;

#pragma unroll
    for (int kc = 0; kc < 2; ++kc) {
        // k = kc*32 + q*8 + 0..7, contiguous within the 128 B node row
        const s16x8* hp = (const s16x8*)(h + (size_t)row * HID + kc * 32 + q * 8);
        s16x8 af = *hp;
#pragma unroll
        for (int ct = 0; ct < 4; ++ct)
            acc[ct] = __builtin_amdgcn_mfma_f32_16x16x32_bf16(af, bfrag[kc][ct], acc[ct], 0, 0, 0);
    }

    float dv[4];
#pragma unroll
    for (int r = 0; r < 4; ++r) {
        int node = node_base + q * 4 + r;
        dv[r] = (node < NNODES) ? dis[node] : 0.f;
    }
#pragma unroll
    for (int ct = 0; ct < 4; ++ct) {
#pragma unroll
        for (int r = 0; r < 4; ++r) {
            int node = node_base + q * 4 + r;
            if (node < NNODES)
                hws[(size_t)node * HID + ct * 16 + m] = f2bf(acc[ct][r] * dv[r]);
        }
    }
}

// ---------------- gather + epilogue (node-major, 8 B/lane gathers) --------
// Wave = 4 dst nodes x 16 lanes; each lane owns cols 4m..4m+3 (8 B of the
// 128 B row). One global_load_dwordx2 per lane per edge; srcs[] already
// holds byte offsets so address math is one v_add_u32. 8-deep unroll for
// memory-level parallelism; gathers hit L2/L3 (12.8 MB working set).
__global__ __launch_bounds__(256) void gather_update(
        const ushort* __restrict__ hws,
        const int* __restrict__ row_ptr, const int* __restrict__ cnt,
        const int* __restrict__ srcs, const float* __restrict__ dis,
        const float* __restrict__ bias,
        const float* __restrict__ g, const float* __restrict__ be,
        const float* __restrict__ mu, const float* __restrict__ var,
        const ushort* __restrict__ last,
        ushort* __restrict__ out_bf, float* __restrict__ out_f,
        int write_f32) {
    const int wave = threadIdx.x >> 6;
    const int lane = threadIdx.x & 63;
    const int d = blockIdx.x * 16 + wave * 4 + (lane >> 4);   // < 100000 exact
    const int m = lane & 15;
    const unsigned int moff = (unsigned int)m * 8u;
    const unsigned int doff = ((unsigned int)d << 7) + moff;

    const char* hb = (const char*)hws;

    uint2 sv = *(const uint2*)(hb + doff);           // self-loop contribution
    float a0 = asf(sv.x << 16), a1 = asf(sv.x & 0xffff0000u);
    float a2 = asf(sv.y << 16), a3 = asf(sv.y & 0xffff0000u);

    const int n = cnt[d];
    const int* sp = srcs + row_ptr[d];

    int k = 0;
    for (; k + 8 <= n; k += 8) {                     // 8 gathers in flight
        unsigned int o0 = (unsigned int)sp[k + 0] + moff;
        unsigned int o1 = (unsigned int)sp[k + 1] + moff;
        unsigned int o2 = (unsigned int)sp[k + 2] + moff;
        unsigned int o3 = (unsigned int)sp[k + 3] + moff;
        unsigned int o4 = (unsigned int)sp[k + 4] + moff;
        unsigned int o5 = (unsigned int)sp[k + 5] + moff;
        unsigned int o6 = (unsigned int)sp[k + 6] + moff;
        unsigned int o7 = (unsigned int)sp[k + 7] + moff;
        uint2 v0 = *(const uint2*)(hb + o0);
        uint2 v1 = *(const uint2*)(hb + o1);
        uint2 v2 = *(const uint2*)(hb + o2);
        uint2 v3 = *(const uint2*)(hb + o3);
        uint2 v4 = *(const uint2*)(hb + o4);
        uint2 v5 = *(const uint2*)(hb + o5);
        uint2 v6 = *(const uint2*)(hb + o6);
        uint2 v7 = *(const uint2*)(hb + o7);
        a0 += asf(v0.x << 16); a1 += asf(v0.x & 0xffff0000u);
        a2 += asf(v0.y << 16); a3 += asf(v0.y & 0xffff0000u);
        a0 += asf(v1.x << 16); a1 += asf(v1.x & 0xffff0000u);
        a2 += asf(v1.y << 16); a3 += asf(v1.y & 0xffff0000u);
        a0 += asf(v2.x << 16); a1 += asf(v2.x & 0xffff0000u);
        a2 += asf(v2.y << 16); a3 += asf(v2.y & 0xffff0000u);
        a0 += asf(v3.x << 16); a1 += asf(v3.x & 0xffff0000u);
        a2 += asf(v3.y << 16); a3 += asf(v3.y & 0xffff0000u);
        a0 += asf(v4.x << 16); a1 += asf(v4.x & 0xffff0000u);
        a2 += asf(v4.y << 16); a3 += asf(v4.y & 0xffff0000u);
        a0 += asf(v5.x << 16); a1 += asf(v5.x & 0xffff0000u);
        a2 += asf(v5.y << 16); a3 += asf(v5.y & 0xffff0000u);
        a0 += asf(v6.x << 16); a1 += asf(v6.x & 0xffff0000u);
        a2 += asf(v6.y << 16); a3 += asf(v6.y & 0xffff0000u);
        a0 += asf(v7.x << 16); a1 += asf(v7.x & 0xffff0000u);
        a2 += asf(v7.y << 16); a3 += asf(v7.y & 0xffff0000u);
    }
    for (; k + 4 <= n; k += 4) {                     // mid tail, 4 in flight
        unsigned int o0 = (unsigned int)sp[k + 0] + moff;
        unsigned int o1 = (unsigned int)sp[k + 1] + moff;
        unsigned int o2 = (unsigned int)sp[k + 2] + moff;
        unsigned int o3 = (unsigned int)sp[k + 3] + moff;
        uint2 v0 = *(const uint2*)(hb + o0);
        uint2 v1 = *(const uint2*)(hb + o1);
        uint2 v2 = *(const uint2*)(hb + o2);
        uint2 v3 = *(const uint2*)(hb + o3);
        a0 += asf(v0.x << 16); a1 += asf(v0.x & 0xffff0000u);
        a2 += asf(v0.y << 16); a3 += asf(v0.y & 0xffff0000u);
        a0 += asf(v1.x << 16); a1 += asf(v1.x & 0xffff0000u);
        a2 += asf(v1.y << 16); a3 += asf(v1.y & 0xffff0000u);
        a0 += asf(v2.x << 16); a1 += asf(v2.x & 0xffff0000u);
        a2 += asf(v2.y << 16); a3 += asf(v2.y & 0xffff0000u);
        a0 += asf(v3.x << 16); a1 += asf(v3.x & 0xffff0000u);
        a2 += asf(v3.y << 16); a3 += asf(v3.y & 0xffff0000u);
    }
    for (; k < n; ++k) {
        uint2 v = *(const uint2*)(hb + ((unsigned int)sp[k] + moff));
        a0 += asf(v.x << 16); a1 += asf(v.x & 0xffff0000u);
        a2 += asf(v.y << 16); a3 += asf(v.y & 0xffff0000u);
    }

    // epilogue: norm + bias + bn + relu + residual (all float4/uint2 I/O)
    float dd = dis[d];
    float4 bi  = ((const float4*)bias)[m];
    float4 gv  = ((const float4*)g)[m];
    float4 bev = ((const float4*)be)[m];
    float4 muv = ((const float4*)mu)[m];
    float4 vav = ((const float4*)var)[m];
    uint2 lv = *(const uint2*)((const char*)last + doff);

    float r0 = fmaxf((a0 * dd + bi.x - muv.x) * (gv.x * rsqrtf(vav.x + BN_EPS)) + bev.x, 0.f)
               + asf(lv.x << 16);
    float r1 = fmaxf((a1 * dd + bi.y - muv.y) * (gv.y * rsqrtf(vav.y + BN_EPS)) + bev.y, 0.f)
               + asf(lv.x & 0xffff0000u);
    float r2 = fmaxf((a2 * dd + bi.z - muv.z) * (gv.z * rsqrtf(vav.z + BN_EPS)) + bev.z, 0.f)
               + asf(lv.y << 16);
    float r3 = fmaxf((a3 * dd + bi.w - muv.w) * (gv.w * rsqrtf(vav.w + BN_EPS)) + bev.w, 0.f)
               + asf(lv.y & 0xffff0000u);

    if (write_f32) {
        ((float4*)out_f)[(size_t)d * 16 + m] = make_float4(r0, r1, r2, r3);  // 256 B/node
    } else {
        uint2 o;
        o.x = (unsigned int)f2bf(r0) | ((unsigned int)f2bf(r1) << 16);
        o.y = (unsigned int)f2bf(r2) | ((unsigned int)f2bf(r3) << 16);
        *(uint2*)((char*)out_bf + doff) = o;                                 // 128 B/node
    }
}

extern "C" void kernel_launch(void* const* d_in, const int* in_sizes, int n_in,
                              void* d_out, int out_size, void* d_ws, size_t ws_size,
                              hipStream_t stream) {
    const float* x      = (const float*)d_in[0];
    const int*   eidx   = (const int*)d_in[1];
    const float* fc_w   = (const float*)d_in[2];
    const float* fc_b   = (const float*)d_in[3];
    const float* conv_w = (const float*)d_in[4];
    const float* conv_b = (const float*)d_in[5];
    const float* bn_g   = (const float*)d_in[6];
    const float* bn_b   = (const float*)d_in[7];
    const float* bn_m   = (const float*)d_in[8];
    const float* bn_v   = (const float*)d_in[9];

    const int* src = eidx;
    const int* dst = eidx + NEDGES;

    float* out = (float*)d_out;       // final output (f32), written once

    // workspace (4B words): dis | cnt | row_ptr | pos | bsum | srcs |
    //                       h0(bf16 node-major) | h1 | hws
    float*  dis     = (float*)d_ws;
    int*    cnt     = (int*)(dis + NPAD);
    int*    row_ptr = cnt + NPAD;
    int*    pos     = row_ptr + NPAD;
    int*    bsum    = pos + NPAD;
    int*    srcs    = bsum + 512;
    ushort* h0      = (ushort*)(srcs + NEDGES);       // N*64 bf16 = 12.8 MB
    ushort* h1      = h0 + (size_t)NNODES * HID;
    ushort* hws     = h1 + (size_t)NNODES * HID;

    const int BLK = 256;
    const int gridN   = (NNODES + BLK - 1) / BLK;
    const int gridF   = FILL_CHUNKS * 8;                 // 4888 (filtered count/fill)
    const int gridMM  = (NNODES + 63) / 64;              // 1563 (MFMA matmuls)

    // CSR build + degree (dst-range partitioned)
    csr_zero<<<gridN, BLK, 0, stream>>>(cnt);
    csr_count<<<gridF, BLK, 0, stream>>>(dst, cnt);
    scan1<<<NSCAN_BLOCKS, 256, 0, stream>>>(cnt, row_ptr, bsum, dis);
    scan2<<<1, 512, 0, stream>>>(bsum);
    scan3<<<gridN, BLK, 0, stream>>>(row_ptr, bsum, pos);
    csr_fill<<<gridF, BLK, 0, stream>>>(src, dst, pos, srcs);

    // fc + bn0 + relu -> h0 (bf16 node-major residual). Never overwritten.
    fc_bn_relu<<<gridMM, BLK, 0, stream>>>(x, fc_w, fc_b, bn_g, bn_b, bn_m, bn_v, h0);

    // layer 1: h0 -> hws -> h1 (bf16 node-major)
    conv_mm<<<gridMM, BLK, 0, stream>>>(h0, conv_w, dis, hws);
    gather_update<<<GBLOCKS, BLK, 0, stream>>>(hws, row_ptr, cnt, srcs, dis,
                                               conv_b, bn_g + HID, bn_b + HID,
                                               bn_m + HID, bn_v + HID, h0,
                                               h1, nullptr, 0);

    // layer 2: h1 -> hws -> out (f32, d_out)
    conv_mm<<<gridMM, BLK, 0, stream>>>(h1, conv_w + HID * HID, dis, hws);
    gather_update<<<GBLOCKS, BLK, 0, stream>>>(hws, row_ptr, cnt, srcs, dis,
                                               conv_b + HID, bn_g + 2 * HID, bn_b + 2 * HID,
                                               bn_m + 2 * HID, bn_v + 2 * HID, h0,
                                               nullptr, out, 1);
}

// Round 2
// 307.484 us; speedup vs baseline: 1.3080x; 1.1586x over previous
//
#include <hip/hip_runtime.h>

#define NNODES 100000
#define NEDGES 1250000
#define IN_CH 128
#define HID 64
#define BN_EPS 1e-5f

#define NPAD 100352               // NNODES rounded to 256 multiple
#define DRANGE 12500              // NNODES / 8 (dst range per XCD)
#define FILL_CHUNK 2048           // edges per block in filtered fill
#define FILL_CHUNKS 611           // ceil(NEDGES / FILL_CHUNK)
#define GBLOCKS 6250              // gather blocks: 16 nodes each (4 waves x 4)
#define ELL_C 32                  // ELL bucket capacity (128 B = d<<7 bytes)
#define OVF_CAP 65536             // overflow list capacity (robustness only)

typedef __attribute__((ext_vector_type(8))) short s16x8;   // 8 bf16 (4 VGPRs)
typedef __attribute__((ext_vector_type(4))) float f32x4;

// bf16 <-> f32 helpers (bit-level, no __hip_bfloat16 class dependence)
__device__ __forceinline__ ushort f2bf(float f) {
    union { float f; unsigned int i; } c;
    c.f = f;
    unsigned int lsb = (c.i >> 16) & 1u;
    return (ushort)((c.i + 0x7FFFu + lsb) >> 16);   // round-to-nearest-even
}
__device__ __forceinline__ float bf2f(ushort u) {
    union { unsigned int i; float f; } c;
    c.i = (unsigned int)u << 16;
    return c.f;
}
__device__ __forceinline__ float asf(unsigned int i) {
    union { unsigned int i; float f; } c;
    c.i = i;
    return c.f;
}

// ---------------- ELL build (dst-range partitioned by XCD) ----------------
__global__ void csr_zero(int* cnt, int* ovf_n) {
    int i = blockIdx.x * blockDim.x + threadIdx.x;
    if (i < NNODES) cnt[i] = 0;
    if (i == 0) *ovf_n = 0;
}

// block b -> XCD b&7 (round-robin dispatch heuristic) -> dst range
// [p*DRANGE, (p+1)*DRANGE). Each XCD streams the whole dst[]/src[] with
// NON-TEMPORAL loads (no L2 pollution) so its ELL write lines stay resident
// in the local L2 and write-allocate merging works. One atomic per edge,
// slot goes straight into the ELL bucket (capacity 32; Poisson(12.5) degree
// overflows with P~1e-6 -> tiny overflow list keeps any input correct).
__global__ void csr_fill(const int* __restrict__ src, const int* __restrict__ dst,
                         int* cnt, int* __restrict__ ell,
                         int* ovf_n, int2* __restrict__ ovf) {
    int p = blockIdx.x & 7;
    int base = (blockIdx.x >> 3) * FILL_CHUNK;
    int lo = p * DRANGE, hi = lo + DRANGE;
#pragma unroll
    for (int k = 0; k < FILL_CHUNK / 256; ++k) {
        int e = base + k * 256 + threadIdx.x;
        if (e < NEDGES) {
            int d = __builtin_nontemporal_load(&dst[e]);
            if (d >= lo && d < hi) {
                int s = __builtin_nontemporal_load(&src[e]);
                int slot = atomicAdd(&cnt[d], 1);
                if (slot < ELL_C) {
                    ell[(d << 5) + slot] = s << 7;   // pre-shifted byte offset
                } else {
                    int oi = atomicAdd(ovf_n, 1);
                    if (oi < OVF_CAP) ovf[oi] = make_int2(d, s << 7);
                }
            }
        }
    }
}

// ---------------- fc + bn0 + relu (MFMA, 16 nodes x 64 cols per wave) -----
// h0 stored NODE-MAJOR: h0[node][64] bf16 = 128 B rows (one gather unit).
// Also emits dis[i] = rsqrt(deg_i + 1) (runs after csr_fill in stream order).
__global__ __launch_bounds__(256) void fc_bn_relu(
        const float* __restrict__ x, const float* __restrict__ w,
        const float* __restrict__ b,
        const float* __restrict__ g, const float* __restrict__ be,
        const float* __restrict__ mu, const float* __restrict__ var,
        const int* __restrict__ cnt, float* __restrict__ dis,
        ushort* __restrict__ h0) {
    const int wave = threadIdx.x >> 6;
    const int lane = threadIdx.x & 63;
    const int m = lane & 15;
    const int q = lane >> 4;
    const int node_base = (blockIdx.x * 4 + wave) * 16;

    if (m == 0) {
#pragma unroll
        for (int r = 0; r < 4; ++r) {
            int node = node_base + q * 4 + r;
            if (node < NNODES) dis[node] = rsqrtf((float)(cnt[node] + 1));
        }
    }

    // B fragments: 4 k-chunks x 4 col-tiles (w is 128x64, L1/L2 resident)
    s16x8 bfrag[4][4];
#pragma unroll
    for (int kc = 0; kc < 4; ++kc)
#pragma unroll
        for (int ct = 0; ct < 4; ++ct)
#pragma unroll
            for (int j = 0; j < 8; ++j)
                bfrag[kc][ct][j] = (short)f2bf(w[(kc * 32 + q * 8 + j) * HID + ct * 16 + m]);

    f32x4 acc[4] = {{0,0,0,0},{0,0,0,0},{0,0,0,0},{0,0,0,0}};

    int row = node_base + m;
    if (row >= NNODES) row = NNODES - 1;             // clamp (stores guarded)
    const float4* xp = (const float4*)(x + (size_t)row * IN_CH + q * 8);

#pragma unroll
    for (int kc = 0; kc < 4; ++kc) {
        float4 a0 = xp[kc * 8 + 0];                  // k = kc*32 + q*8 + 0..3
        float4 a1 = xp[kc * 8 + 1];                  // k = kc*32 + q*8 + 4..7
        s16x8 af;
        af[0] = (short)f2bf(a0.x); af[1] = (short)f2bf(a0.y);
        af[2] = (short)f2bf(a0.z); af[3] = (short)f2bf(a0.w);
        af[4] = (short)f2bf(a1.x); af[5] = (short)f2bf(a1.y);
        af[6] = (short)f2bf(a1.z); af[7] = (short)f2bf(a1.w);
#pragma unroll
        for (int ct = 0; ct < 4; ++ct)
            acc[ct] = __builtin_amdgcn_mfma_f32_16x16x32_bf16(af, bfrag[kc][ct], acc[ct], 0, 0, 0);
    }

#pragma unroll
    for (int ct = 0; ct < 4; ++ct) {
        int col = ct * 16 + m;
        float sc = g[col] * rsqrtf(var[col] + BN_EPS);
        float off = (b[col] - mu[col]) * sc + be[col];
#pragma unroll
        for (int r = 0; r < 4; ++r) {
            int node = node_base + q * 4 + r;
            if (node < NNODES)
                h0[(size_t)node * HID + col] =
                    f2bf(fmaxf(acc[ct][r] * sc + off, 0.f));
        }
    }
}

// ---------------- conv matmul + source-side dis scale (MFMA) --------------
// h (bf16, node-major) -> hws (bf16, node-major), K = 64
__global__ __launch_bounds__(256) void conv_mm(
        const ushort* __restrict__ h, const float* __restrict__ w,
        const float* __restrict__ dis, ushort* __restrict__ hws) {
    const int wave = threadIdx.x >> 6;
    const int lane = threadIdx.x & 63;
    const int m = lane & 15;
    const int q = lane >> 4;
    const int node_base = (blockIdx.x * 4 + wave) * 16;

    s16x8 bfrag[2][4];
#pragma unroll
    for (int kc = 0; kc < 2; ++kc)
#pragma unroll
        for (int ct = 0; ct < 4; ++ct)
#pragma unroll
            for (int j = 0; j < 8; ++j)
                bfrag[kc][ct][j] = (short)f2bf(w[(kc * 32 + q * 8 + j) * HID + ct * 16 + m]);

    f32x4 acc[4] = {{0,0,0,0},{0,0,0,0},{0,0,0,0},{0,0,0,0}};

    int row = node_base + m;
    if (row >= NNODES) row = NNODES - 1;

#pragma unroll
    for (int kc = 0; kc < 2; ++kc) {
        // k = kc*32 + q*8 + 0..7, contiguous within the 128 B node row
        const s16x8* hp = (const s16x8*)(h + (size_t)row * HID + kc * 32 + q * 8);
        s16x8 af = *hp;
#pragma unroll
        for (int ct = 0; ct < 4; ++ct)
            acc[ct] = __builtin_amdgcn_mfma_f32_16x16x32_bf16(af, bfrag[kc][ct], acc[ct], 0, 0, 0);
    }

    float dv[4];
#pragma unroll
    for (int r = 0; r < 4; ++r) {
        int node = node_base + q * 4 + r;
        dv[r] = (node < NNODES) ? dis[node] : 0.f;
    }
#pragma unroll
    for (int ct = 0; ct < 4; ++ct) {
#pragma unroll
        for (int r = 0; r < 4; ++r) {
            int node = node_base + q * 4 + r;
            if (node < NNODES)
                hws[(size_t)node * HID + ct * 16 + m] = f2bf(acc[ct][r] * dv[r]);
        }
    }
}

// ---------------- gather + epilogue (node-major, 8 B/lane gathers) --------
// Wave = 4 dst nodes x 16 lanes; each lane owns cols 4m..4m+3 (8 B of the
// 128 B row). One global_load_dwordx2 per lane per edge from the ELL bucket
// (contiguous per dst); 8-deep unroll for memory-level parallelism.
__global__ __launch_bounds__(256) void gather_update(
        const ushort* __restrict__ hws,
        const int* __restrict__ cnt, const int* __restrict__ ell,
        const int* __restrict__ ovf_n, const int2* __restrict__ ovf,
        const float* __restrict__ dis,
        const float* __restrict__ bias,
        const float* __restrict__ g, const float* __restrict__ be,
        const float* __restrict__ mu, const float* __restrict__ var,
        const ushort* __restrict__ last,
        ushort* __restrict__ out_bf, float* __restrict__ out_f,
        int write_f32) {
    const int wave = threadIdx.x >> 6;
    const int lane = threadIdx.x & 63;
    const int d = blockIdx.x * 16 + wave * 4 + (lane >> 4);   // < 100000 exact
    const int m = lane & 15;
    const unsigned int moff = (unsigned int)m * 8u;
    const unsigned int doff = ((unsigned int)d << 7) + moff;

    const char* hb = (const char*)hws;

    uint2 sv = *(const uint2*)(hb + doff);           // self-loop contribution
    float a0 = asf(sv.x << 16), a1 = asf(sv.x & 0xffff0000u);
    float a2 = asf(sv.y << 16), a3 = asf(sv.y & 0xffff0000u);

    const int n = cnt[d];
    const int nn = (n < ELL_C) ? n : ELL_C;
    const int* sp = ell + ((size_t)d << 5);

    int k = 0;
    for (; k + 8 <= nn; k += 8) {                    // 8 gathers in flight
        unsigned int o0 = (unsigned int)sp[k + 0] + moff;
        unsigned int o1 = (unsigned int)sp[k + 1] + moff;
        unsigned int o2 = (unsigned int)sp[k + 2] + moff;
        unsigned int o3 = (unsigned int)sp[k + 3] + moff;
        unsigned int o4 = (unsigned int)sp[k + 4] + moff;
        unsigned int o5 = (unsigned int)sp[k + 5] + moff;
        unsigned int o6 = (unsigned int)sp[k + 6] + moff;
        unsigned int o7 = (unsigned int)sp[k + 7] + moff;
        uint2 v0 = *(const uint2*)(hb + o0);
        uint2 v1 = *(const uint2*)(hb + o1);
        uint2 v2 = *(const uint2*)(hb + o2);
        uint2 v3 = *(const uint2*)(hb + o3);
        uint2 v4 = *(const uint2*)(hb + o4);
        uint2 v5 = *(const uint2*)(hb + o5);
        uint2 v6 = *(const uint2*)(hb + o6);
        uint2 v7 = *(const uint2*)(hb + o7);
        a0 += asf(v0.x << 16); a1 += asf(v0.x & 0xffff0000u);
        a2 += asf(v0.y << 16); a3 += asf(v0.y & 0xffff0000u);
        a0 += asf(v1.x << 16); a1 += asf(v1.x & 0xffff0000u);
        a2 += asf(v1.y << 16); a3 += asf(v1.y & 0xffff0000u);
        a0 += asf(v2.x << 16); a1 += asf(v2.x & 0xffff0000u);
        a2 += asf(v2.y << 16); a3 += asf(v2.y & 0xffff0000u);
        a0 += asf(v3.x << 16); a1 += asf(v3.x & 0xffff0000u);
        a2 += asf(v3.y << 16); a3 += asf(v3.y & 0xffff0000u);
        a0 += asf(v4.x << 16); a1 += asf(v4.x & 0xffff0000u);
        a2 += asf(v4.y << 16); a3 += asf(v4.y & 0xffff0000u);
        a0 += asf(v5.x << 16); a1 += asf(v5.x & 0xffff0000u);
        a2 += asf(v5.y << 16); a3 += asf(v5.y & 0xffff0000u);
        a0 += asf(v6.x << 16); a1 += asf(v6.x & 0xffff0000u);
        a2 += asf(v6.y << 16); a3 += asf(v6.y & 0xffff0000u);
        a0 += asf(v7.x << 16); a1 += asf(v7.x & 0xffff0000u);
        a2 += asf(v7.y << 16); a3 += asf(v7.y & 0xffff0000u);
    }
    for (; k + 4 <= nn; k += 4) {                    // mid tail, 4 in flight
        unsigned int o0 = (unsigned int)sp[k + 0] + moff;
        unsigned int o1 = (unsigned int)sp[k + 1] + moff;
        unsigned int o2 = (unsigned int)sp[k + 2] + moff;
        unsigned int o3 = (unsigned int)sp[k + 3] + moff;
        uint2 v0 = *(const uint2*)(hb + o0);
        uint2 v1 = *(const uint2*)(hb + o1);
        uint2 v2 = *(const uint2*)(hb + o2);
        uint2 v3 = *(const uint2*)(hb + o3);
        a0 += asf(v0.x << 16); a1 += asf(v0.x & 0xffff0000u);
        a2 += asf(v0.y << 16); a3 += asf(v0.y & 0xffff0000u);
        a0 += asf(v1.x << 16); a1 += asf(v1.x & 0xffff0000u);
        a2 += asf(v1.y << 16); a3 += asf(v1.y & 0xffff0000u);
        a0 += asf(v2.x << 16); a1 += asf(v2.x & 0xffff0000u);
        a2 += asf(v2.y << 16); a3 += asf(v2.y & 0xffff0000u);
        a0 += asf(v3.x << 16); a1 += asf(v3.x & 0xffff0000u);
        a2 += asf(v3.y << 16); a3 += asf(v3.y & 0xffff0000u);
    }
    for (; k < nn; ++k) {
        uint2 v = *(const uint2*)(hb + ((unsigned int)sp[k] + moff));
        a0 += asf(v.x << 16); a1 += asf(v.x & 0xffff0000u);
        a2 += asf(v.y << 16); a3 += asf(v.y & 0xffff0000u);
    }
    if (n > ELL_C) {                                 // rare overflow path
        int on = *ovf_n;
        if (on > OVF_CAP) on = OVF_CAP;
        for (int j = 0; j < on; ++j) {
            int2 e = ovf[j];
            if (e.x == d) {
                uint2 v = *(const uint2*)(hb + ((unsigned int)e.y + moff));
                a0 += asf(v.x << 16); a1 += asf(v.x & 0xffff0000u);
                a2 += asf(v.y << 16); a3 += asf(v.y & 0xffff0000u);
            }
        }
    }

    // epilogue: norm + bias + bn + relu + residual (all float4/uint2 I/O)
    float dd = dis[d];
    float4 bi  = ((const float4*)bias)[m];
    float4 gv  = ((const float4*)g)[m];
    float4 bev = ((const float4*)be)[m];
    float4 muv = ((const float4*)mu)[m];
    float4 vav = ((const float4*)var)[m];
    uint2 lv = *(const uint2*)((const char*)last + doff);

    float r0 = fmaxf((a0 * dd + bi.x - muv.x) * (gv.x * rsqrtf(vav.x + BN_EPS)) + bev.x, 0.f)
               + asf(lv.x << 16);
    float r1 = fmaxf((a1 * dd + bi.y - muv.y) * (gv.y * rsqrtf(vav.y + BN_EPS)) + bev.y, 0.f)
               + asf(lv.x & 0xffff0000u);
    float r2 = fmaxf((a2 * dd + bi.z - muv.z) * (gv.z * rsqrtf(vav.z + BN_EPS)) + bev.z, 0.f)
               + asf(lv.y << 16);
    float r3 = fmaxf((a3 * dd + bi.w - muv.w) * (gv.w * rsqrtf(vav.w + BN_EPS)) + bev.w, 0.f)
               + asf(lv.y & 0xffff0000u);

    if (write_f32) {
        ((float4*)out_f)[(size_t)d * 16 + m] = make_float4(r0, r1, r2, r3);  // 256 B/node
    } else {
        uint2 o;
        o.x = (unsigned int)f2bf(r0) | ((unsigned int)f2bf(r1) << 16);
        o.y = (unsigned int)f2bf(r2) | ((unsigned int)f2bf(r3) << 16);
        *(uint2*)((char*)out_bf + doff) = o;                                 // 128 B/node
    }
}

extern "C" void kernel_launch(void* const* d_in, const int* in_sizes, int n_in,
                              void* d_out, int out_size, void* d_ws, size_t ws_size,
                              hipStream_t stream) {
    const float* x      = (const float*)d_in[0];
    const int*   eidx   = (const int*)d_in[1];
    const float* fc_w   = (const float*)d_in[2];
    const float* fc_b   = (const float*)d_in[3];
    const float* conv_w = (const float*)d_in[4];
    const float* conv_b = (const float*)d_in[5];
    const float* bn_g   = (const float*)d_in[6];
    const float* bn_b   = (const float*)d_in[7];
    const float* bn_m   = (const float*)d_in[8];
    const float* bn_v   = (const float*)d_in[9];

    const int* src = eidx;
    const int* dst = eidx + NEDGES;

    float* out = (float*)d_out;       // final output (f32), written once

    // workspace (4B words): dis | cnt | ovf_n | ovf | ell | h0 | h1 | hws
    float*  dis     = (float*)d_ws;
    int*    cnt     = (int*)(dis + NPAD);
    int*    ovf_n   = cnt + NPAD;
    int2*   ovf     = (int2*)(ovf_n + 4);             // 8B-aligned
    int*    ell     = (int*)(ovf + OVF_CAP);          // N*32 ints = 12.8 MB
    ushort* h0      = (ushort*)(ell + (size_t)NNODES * ELL_C);  // N*64 bf16
    ushort* h1      = h0 + (size_t)NNODES * HID;
    ushort* hws     = h1 + (size_t)NNODES * HID;

    const int BLK = 256;
    const int gridN   = (NNODES + BLK - 1) / BLK;
    const int gridF   = FILL_CHUNKS * 8;                 // 4888 (filtered fill)
    const int gridMM  = (NNODES + 63) / 64;              // 1563 (MFMA matmuls)

    // ELL build + degree (dst-range partitioned, single filtered pass)
    csr_zero<<<gridN, BLK, 0, stream>>>(cnt, ovf_n);
    csr_fill<<<gridF, BLK, 0, stream>>>(src, dst, cnt, ell, ovf_n, ovf);

    // fc + bn0 + relu -> h0 (bf16 node-major residual) + dis from degrees
    fc_bn_relu<<<gridMM, BLK, 0, stream>>>(x, fc_w, fc_b, bn_g, bn_b, bn_m, bn_v,
                                           cnt, dis, h0);

    // layer 1: h0 -> hws -> h1 (bf16 node-major)
    conv_mm<<<gridMM, BLK, 0, stream>>>(h0, conv_w, dis, hws);
    gather_update<<<GBLOCKS, BLK, 0, stream>>>(hws, cnt, ell, ovf_n, ovf, dis,
                                               conv_b, bn_g + HID, bn_b + HID,
                                               bn_m + HID, bn_v + HID, h0,
                                               h1, nullptr, 0);

    // layer 2: h1 -> hws -> out (f32, d_out)
    conv_mm<<<gridMM, BLK, 0, stream>>>(h1, conv_w + HID * HID, dis, hws);
    gather_update<<<GBLOCKS, BLK, 0, stream>>>(hws, cnt, ell, ovf_n, ovf, dis,
                                               conv_b + HID, bn_g + 2 * HID, bn_b + 2 * HID,
                                               bn_m + 2 * HID, bn_v + 2 * HID, h0,
                                               nullptr, out, 1);
}